// Round 1
// baseline (9742.869 us; speedup 1.0000x reference)
//
#include <hip/hip_runtime.h>

#define L_DIM 1024
#define B_DIM 128
#define I_DIM 256
#define H_DIM 512

typedef unsigned short u16x8 __attribute__((ext_vector_type(8)));
typedef __bf16 bf16x8 __attribute__((ext_vector_type(8)));
typedef float f32x4 __attribute__((ext_vector_type(4)));

static __device__ __forceinline__ unsigned short f2bf(float f) {
  unsigned u = __builtin_bit_cast(unsigned, f);
  u += 0x7FFFu + ((u >> 16) & 1u);
  return (unsigned short)(u >> 16);
}
static __device__ __forceinline__ float bf2f(unsigned short b) {
  return __builtin_bit_cast(float, ((unsigned)b) << 16);
}
static __device__ __forceinline__ bf16x8 ld_frag_g(const unsigned short* p, size_t idx8) {
  return __builtin_bit_cast(bf16x8, reinterpret_cast<const u16x8*>(p)[idx8]);
}

// ---------------------------------------------------------------------------
// Pack Wx and Wh into MFMA B-fragment order, split hi/lo bf16.
// B-frag for mfma_f32_16x16x32_bf16: lane l holds B[k = kt*32+(l>>4)*8+j][n = nt*16+(l&15)]
// where source matrix is W[n][k] (we need z[b,n] = sum_k h[b,k]*W[n,k]).
// Layout: pack[((nt*KT + kt)*64 + lane)*8 + j]
// ---------------------------------------------------------------------------
__global__ void pack_weights(const float* __restrict__ Wx, const float* __restrict__ Wh,
                             unsigned short* __restrict__ WxHi, unsigned short* __restrict__ WxLo,
                             unsigned short* __restrict__ WhHi, unsigned short* __restrict__ WhLo) {
  int tid = blockIdx.x * blockDim.x + threadIdx.x;
  if (tid < 32 * 8 * 64) {  // Wx: 32 ntiles x 8 ktiles (K=256)
    int lane = tid & 63, kt = (tid >> 6) & 7, nt = tid >> 9;
    int n = nt * 16 + (lane & 15), k0 = kt * 32 + (lane >> 4) * 8;
    const float* src = Wx + (size_t)n * I_DIM + k0;
    #pragma unroll
    for (int j = 0; j < 8; ++j) {
      float v = src[j];
      unsigned short hb = f2bf(v);
      WxHi[(size_t)tid * 8 + j] = hb;
      WxLo[(size_t)tid * 8 + j] = f2bf(v - bf2f(hb));
    }
  }
  if (tid < 32 * 16 * 64) {  // Wh: 32 ntiles x 16 ktiles (K=512)
    int lane = tid & 63, kt = (tid >> 6) & 15, nt = tid >> 10;
    int n = nt * 16 + (lane & 15), k0 = kt * 32 + (lane >> 4) * 8;
    const float* src = Wh + (size_t)n * H_DIM + k0;
    #pragma unroll
    for (int j = 0; j < 8; ++j) {
      float v = src[j];
      unsigned short hb = f2bf(v);
      WhHi[(size_t)tid * 8 + j] = hb;
      WhLo[(size_t)tid * 8 + j] = f2bf(v - bf2f(hb));
    }
  }
}

// ---------------------------------------------------------------------------
// xproj: out[m, n] = sum_k x[m,k]*Wx[n,k] + bh[n], m = l*B+b flattened (131072),
// K=256, N=512. 128x128 tiles, 256 threads (4 waves, 2x2 of 64x64).
// fp32 precision via 3-product bf16 hi/lo split (x_hi*W_hi + x_lo*W_hi + x_hi*W_lo).
// Writes xp into d_out (consumed and overwritten by rnn_kernel).
// ---------------------------------------------------------------------------
__global__ __launch_bounds__(256) void xproj_kernel(const float* __restrict__ x,
    const unsigned short* __restrict__ WxHi, const unsigned short* __restrict__ WxLo,
    const float* __restrict__ bh, float* __restrict__ out) {
  __shared__ unsigned short ahi[128][40];  // +8 pad: 2-way LDS bank aliasing (free)
  __shared__ unsigned short alo[128][40];
  const int tid = threadIdx.x, lane = tid & 63, wid = tid >> 6;
  const int mbase = blockIdx.x * 128, cbase = blockIdx.y * 128;
  const int wrow = (wid >> 1) * 64, wcol = (wid & 1) * 64;
  f32x4 acc[4][4] = {};
  const int srow = tid >> 1, shalf = (tid & 1) * 16;

  for (int kt = 0; kt < 8; ++kt) {
    // ---- stage 128x32 fp32 -> hi/lo bf16 in LDS ----
    const f32x4* src = reinterpret_cast<const f32x4*>(
        x + (size_t)(mbase + srow) * I_DIM + kt * 32 + shalf);
    f32x4 v[4];
    v[0] = src[0]; v[1] = src[1]; v[2] = src[2]; v[3] = src[3];
    u16x8 hh[2], ll[2];
    #pragma unroll
    for (int q = 0; q < 2; ++q) {
      #pragma unroll
      for (int e = 0; e < 8; ++e) {
        float f = v[q * 2 + (e >> 2)][e & 3];
        unsigned short hb = f2bf(f);
        hh[q][e] = hb;
        ll[q][e] = f2bf(f - bf2f(hb));
      }
    }
    __syncthreads();  // previous iteration's fragment reads complete
    *reinterpret_cast<u16x8*>(&ahi[srow][shalf]) = hh[0];
    *reinterpret_cast<u16x8*>(&ahi[srow][shalf + 8]) = hh[1];
    *reinterpret_cast<u16x8*>(&alo[srow][shalf]) = ll[0];
    *reinterpret_cast<u16x8*>(&alo[srow][shalf + 8]) = ll[1];
    __syncthreads();

    // ---- fragments + MFMA ----
    bf16x8 amh[4], aml[4];
    #pragma unroll
    for (int m = 0; m < 4; ++m) {
      amh[m] = __builtin_bit_cast(bf16x8, *reinterpret_cast<const u16x8*>(
          &ahi[wrow + m * 16 + (lane & 15)][(lane >> 4) * 8]));
      aml[m] = __builtin_bit_cast(bf16x8, *reinterpret_cast<const u16x8*>(
          &alo[wrow + m * 16 + (lane & 15)][(lane >> 4) * 8]));
    }
    bf16x8 bhh[4], bll[4];
    #pragma unroll
    for (int n = 0; n < 4; ++n) {
      int ntg = (cbase + wcol) / 16 + n;
      size_t idx = (size_t)(ntg * 8 + kt) * 64 + lane;
      bhh[n] = ld_frag_g(WxHi, idx);
      bll[n] = ld_frag_g(WxLo, idx);
    }
    #pragma unroll
    for (int m = 0; m < 4; ++m) {
      #pragma unroll
      for (int n = 0; n < 4; ++n) {
        acc[m][n] = __builtin_amdgcn_mfma_f32_16x16x32_bf16(amh[m], bhh[n], acc[m][n], 0, 0, 0);
        acc[m][n] = __builtin_amdgcn_mfma_f32_16x16x32_bf16(aml[m], bhh[n], acc[m][n], 0, 0, 0);
        acc[m][n] = __builtin_amdgcn_mfma_f32_16x16x32_bf16(amh[m], bll[n], acc[m][n], 0, 0, 0);
      }
    }
  }

  // ---- epilogue: + bh, store fp32 (D layout: col=lane&15, row=(lane>>4)*4+r) ----
  #pragma unroll
  for (int n = 0; n < 4; ++n) {
    int col = cbase + wcol + n * 16 + (lane & 15);
    float bv = bh[col];
    #pragma unroll
    for (int m = 0; m < 4; ++m) {
      int rg = mbase + wrow + m * 16 + ((lane >> 4) << 2);
      #pragma unroll
      for (int r = 0; r < 4; ++r)
        out[(size_t)(rg + r) * H_DIM + col] = acc[m][n][r] + bv;
    }
  }
}

// ---------------------------------------------------------------------------
// Recurrence: 8 WGs x 512 threads; WG g owns batch rows 16g..16g+15 for all
// 1024 steps (batch-parallel => no cross-WG sync). h kept in LDS as bf16
// (double-buffered); Wh_hi/Wh_lo streamed from L2 as packed fragments.
// z = Whi*h + Wlo*h (+ xp, already includes bh); h_new = tanh(z).
// ---------------------------------------------------------------------------
__global__ __launch_bounds__(512) void rnn_kernel(const float* __restrict__ h0,
    const unsigned short* __restrict__ WhHi, const unsigned short* __restrict__ WhLo,
    float* __restrict__ out) {
  __shared__ unsigned short hbuf[2][16][520];  // +8 pad
  const int tid = threadIdx.x, lane = tid & 63, wid = tid >> 6;
  const int g = blockIdx.x;
  for (int i = tid; i < 16 * H_DIM; i += 512) {
    int row = i >> 9, col = i & 511;
    hbuf[0][row][col] = f2bf(h0[(size_t)(g * 16 + row) * H_DIM + col]);
  }
  __syncthreads();
  const int wcol = wid * 64;
  const int arow = lane & 15;        // A row / D col within 16
  const int aoff = (lane >> 4) * 8;  // A k offset
  const int drow = (lane >> 4) * 4;  // D row base

  for (int t = 0; t < 1024; ++t) {
    const int cur = t & 1;
    const size_t obase = ((size_t)t * B_DIM + g * 16) * H_DIM;

    // issue xp loads early; latency hides under the MFMA loop
    f32x4 xpv[4];
    #pragma unroll
    for (int nt = 0; nt < 4; ++nt) {
      int col = wcol + nt * 16 + arow;
      #pragma unroll
      for (int r = 0; r < 4; ++r)
        xpv[nt][r] = out[obase + (size_t)(drow + r) * H_DIM + col];
    }

    f32x4 acc[4] = {};
    #pragma unroll 4
    for (int kt = 0; kt < 16; ++kt) {
      bf16x8 a = __builtin_bit_cast(bf16x8, *reinterpret_cast<const u16x8*>(
          &hbuf[cur][arow][kt * 32 + aoff]));
      #pragma unroll
      for (int nt = 0; nt < 4; ++nt) {
        size_t idx = (size_t)((wid * 4 + nt) * 16 + kt) * 64 + lane;
        bf16x8 bhi = ld_frag_g(WhHi, idx);
        bf16x8 blo = ld_frag_g(WhLo, idx);
        acc[nt] = __builtin_amdgcn_mfma_f32_16x16x32_bf16(a, bhi, acc[nt], 0, 0, 0);
        acc[nt] = __builtin_amdgcn_mfma_f32_16x16x32_bf16(a, blo, acc[nt], 0, 0, 0);
      }
    }

    #pragma unroll
    for (int nt = 0; nt < 4; ++nt) {
      int col = wcol + nt * 16 + arow;
      #pragma unroll
      for (int r = 0; r < 4; ++r) {
        float z = acc[nt][r] + xpv[nt][r];
        float e = __expf(2.0f * z);
        float hv = 1.0f - 2.0f / (e + 1.0f);  // tanh(z), saturates correctly
        out[obase + (size_t)(drow + r) * H_DIM + col] = hv;
        hbuf[cur ^ 1][drow + r][col] = f2bf(hv);
      }
    }
    __syncthreads();  // h_new (buffer cur^1) visible before next step reads it
  }
}

extern "C" void kernel_launch(void* const* d_in, const int* in_sizes, int n_in,
                              void* d_out, int out_size, void* d_ws, size_t ws_size,
                              hipStream_t stream) {
  (void)in_sizes; (void)n_in; (void)out_size; (void)ws_size;
  const float* x  = (const float*)d_in[0];
  const float* h0 = (const float*)d_in[1];
  const float* Wx = (const float*)d_in[2];
  const float* Wh = (const float*)d_in[3];
  const float* bh = (const float*)d_in[4];
  float* out = (float*)d_out;

  unsigned short* WxHi = (unsigned short*)d_ws;       // 131072 elems
  unsigned short* WxLo = WxHi + 131072;
  unsigned short* WhHi = WxLo + 131072;               // 262144 elems
  unsigned short* WhLo = WhHi + 262144;               // total 1.5 MB

  hipLaunchKernelGGL(pack_weights, dim3(128), dim3(256), 0, stream,
                     Wx, Wh, WxHi, WxLo, WhHi, WhLo);
  hipLaunchKernelGGL(xproj_kernel, dim3(1024, 4), dim3(256), 0, stream,
                     x, WxHi, WxLo, bh, out);
  hipLaunchKernelGGL(rnn_kernel, dim3(8), dim3(512), 0, stream,
                     h0, WhHi, WhLo, out);
}

// Round 2
// 7889.982 us; speedup vs baseline: 1.2348x; 1.2348x over previous
//
#include <hip/hip_runtime.h>

#define L_DIM 1024
#define B_DIM 128
#define I_DIM 256
#define H_DIM 512

typedef unsigned short u16x8 __attribute__((ext_vector_type(8)));
typedef __bf16 bf16x8 __attribute__((ext_vector_type(8)));
typedef float f32x4 __attribute__((ext_vector_type(4)));

static __device__ __forceinline__ unsigned short f2bf(float f) {
  unsigned u = __builtin_bit_cast(unsigned, f);
  u += 0x7FFFu + ((u >> 16) & 1u);
  return (unsigned short)(u >> 16);
}
static __device__ __forceinline__ float bf2f(unsigned short b) {
  return __builtin_bit_cast(float, ((unsigned)b) << 16);
}
static __device__ __forceinline__ bf16x8 ld_frag_g(const unsigned short* p, size_t idx8) {
  return __builtin_bit_cast(bf16x8, reinterpret_cast<const u16x8*>(p)[idx8]);
}

// ---------------------------------------------------------------------------
// Pack Wx and Wh into MFMA B-fragment order, split hi/lo bf16.
// B-frag: lane l holds B[k = kt*32+(l>>4)*8+j][n = nt*16+(l&15)], W stored [n][k].
// Layout: pack[((nt*KT + kt)*64 + lane)*8 + j]
// ---------------------------------------------------------------------------
__global__ void pack_weights(const float* __restrict__ Wx, const float* __restrict__ Wh,
                             unsigned short* __restrict__ WxHi, unsigned short* __restrict__ WxLo,
                             unsigned short* __restrict__ WhHi, unsigned short* __restrict__ WhLo) {
  int tid = blockIdx.x * blockDim.x + threadIdx.x;
  if (tid < 32 * 8 * 64) {  // Wx: 32 ntiles x 8 ktiles (K=256)
    int lane = tid & 63, kt = (tid >> 6) & 7, nt = tid >> 9;
    int n = nt * 16 + (lane & 15), k0 = kt * 32 + (lane >> 4) * 8;
    const float* src = Wx + (size_t)n * I_DIM + k0;
    #pragma unroll
    for (int j = 0; j < 8; ++j) {
      float v = src[j];
      unsigned short hb = f2bf(v);
      WxHi[(size_t)tid * 8 + j] = hb;
      WxLo[(size_t)tid * 8 + j] = f2bf(v - bf2f(hb));
    }
  }
  if (tid < 32 * 16 * 64) {  // Wh: 32 ntiles x 16 ktiles (K=512)
    int lane = tid & 63, kt = (tid >> 6) & 15, nt = tid >> 10;
    int n = nt * 16 + (lane & 15), k0 = kt * 32 + (lane >> 4) * 8;
    const float* src = Wh + (size_t)n * H_DIM + k0;
    #pragma unroll
    for (int j = 0; j < 8; ++j) {
      float v = src[j];
      unsigned short hb = f2bf(v);
      WhHi[(size_t)tid * 8 + j] = hb;
      WhLo[(size_t)tid * 8 + j] = f2bf(v - bf2f(hb));
    }
  }
}

// ---------------------------------------------------------------------------
// xproj: out[m,n] = sum_k x[m,k]*Wx[n,k] + bh[n]  (unchanged from R1)
// ---------------------------------------------------------------------------
__global__ __launch_bounds__(256) void xproj_kernel(const float* __restrict__ x,
    const unsigned short* __restrict__ WxHi, const unsigned short* __restrict__ WxLo,
    const float* __restrict__ bh, float* __restrict__ out) {
  __shared__ unsigned short ahi[128][40];
  __shared__ unsigned short alo[128][40];
  const int tid = threadIdx.x, lane = tid & 63, wid = tid >> 6;
  const int mbase = blockIdx.x * 128, cbase = blockIdx.y * 128;
  const int wrow = (wid >> 1) * 64, wcol = (wid & 1) * 64;
  f32x4 acc[4][4] = {};
  const int srow = tid >> 1, shalf = (tid & 1) * 16;

  for (int kt = 0; kt < 8; ++kt) {
    const f32x4* src = reinterpret_cast<const f32x4*>(
        x + (size_t)(mbase + srow) * I_DIM + kt * 32 + shalf);
    f32x4 v[4];
    v[0] = src[0]; v[1] = src[1]; v[2] = src[2]; v[3] = src[3];
    u16x8 hh[2], ll[2];
    #pragma unroll
    for (int q = 0; q < 2; ++q) {
      #pragma unroll
      for (int e = 0; e < 8; ++e) {
        float f = v[q * 2 + (e >> 2)][e & 3];
        unsigned short hb = f2bf(f);
        hh[q][e] = hb;
        ll[q][e] = f2bf(f - bf2f(hb));
      }
    }
    __syncthreads();
    *reinterpret_cast<u16x8*>(&ahi[srow][shalf]) = hh[0];
    *reinterpret_cast<u16x8*>(&ahi[srow][shalf + 8]) = hh[1];
    *reinterpret_cast<u16x8*>(&alo[srow][shalf]) = ll[0];
    *reinterpret_cast<u16x8*>(&alo[srow][shalf + 8]) = ll[1];
    __syncthreads();

    bf16x8 amh[4], aml[4];
    #pragma unroll
    for (int m = 0; m < 4; ++m) {
      amh[m] = __builtin_bit_cast(bf16x8, *reinterpret_cast<const u16x8*>(
          &ahi[wrow + m * 16 + (lane & 15)][(lane >> 4) * 8]));
      aml[m] = __builtin_bit_cast(bf16x8, *reinterpret_cast<const u16x8*>(
          &alo[wrow + m * 16 + (lane & 15)][(lane >> 4) * 8]));
    }
    bf16x8 bhh[4], bll[4];
    #pragma unroll
    for (int n = 0; n < 4; ++n) {
      int ntg = (cbase + wcol) / 16 + n;
      size_t idx = (size_t)(ntg * 8 + kt) * 64 + lane;
      bhh[n] = ld_frag_g(WxHi, idx);
      bll[n] = ld_frag_g(WxLo, idx);
    }
    #pragma unroll
    for (int m = 0; m < 4; ++m) {
      #pragma unroll
      for (int n = 0; n < 4; ++n) {
        acc[m][n] = __builtin_amdgcn_mfma_f32_16x16x32_bf16(amh[m], bhh[n], acc[m][n], 0, 0, 0);
        acc[m][n] = __builtin_amdgcn_mfma_f32_16x16x32_bf16(aml[m], bhh[n], acc[m][n], 0, 0, 0);
        acc[m][n] = __builtin_amdgcn_mfma_f32_16x16x32_bf16(amh[m], bll[n], acc[m][n], 0, 0, 0);
      }
    }
  }

  #pragma unroll
  for (int n = 0; n < 4; ++n) {
    int col = cbase + wcol + n * 16 + (lane & 15);
    float bv = bh[col];
    #pragma unroll
    for (int m = 0; m < 4; ++m) {
      int rg = mbase + wrow + m * 16 + ((lane >> 4) << 2);
      #pragma unroll
      for (int r = 0; r < 4; ++r)
        out[(size_t)(rg + r) * H_DIM + col] = acc[m][n][r] + bv;
    }
  }
}

// ---------------------------------------------------------------------------
// Recurrence, LDS-resident Wh slices.
// 64 WGs x 256 thr: g = blk&7 (16 batch rows), c = blk>>3 (64 output cols).
// Wh hi+lo slice (128 KB) lives in dynamic LDS for all 1024 steps.
// Per step: z = h_t . Wh_slice (hi+lo) + xp; h_{t+1} = tanh(z); exchange h
// slices among the 8 col-WGs of a batch group via global bf16 buffer +
// device-scope counter (memset to 0 by host each launch).
// ---------------------------------------------------------------------------
__global__ __launch_bounds__(256) void rnn_kernel(const float* __restrict__ h0,
    const unsigned short* __restrict__ WhHi, const unsigned short* __restrict__ WhLo,
    unsigned int* __restrict__ ctr, unsigned short* __restrict__ gbuf,
    float* __restrict__ out) {
  extern __shared__ unsigned short smem[];
  unsigned short* wh = smem;            // [hilo=2][ntl=4][kt=16][lane=64][8] = 65536 u16
  unsigned short* hb = smem + 65536;    // [16][520] bf16 h_t
  const int tid = threadIdx.x, lane = tid & 63, w = tid >> 6;
  const int g = blockIdx.x & 7, c = blockIdx.x >> 3;

  // ---- one-time staging: Wh slice -> LDS, h0 -> LDS ----
  {
    u16x8* whv = reinterpret_cast<u16x8*>(wh);
    const u16x8* hiv = reinterpret_cast<const u16x8*>(WhHi) + (size_t)c * 4096;
    const u16x8* lov = reinterpret_cast<const u16x8*>(WhLo) + (size_t)c * 4096;
    for (int i = tid; i < 4096; i += 256) {
      whv[i] = hiv[i];
      whv[4096 + i] = lov[i];
    }
    for (int i = tid; i < 1024; i += 256) {  // 16x512 f32, 8 at a time
      int row = i >> 6, col0 = (i & 63) * 8;
      const f32x4* s = reinterpret_cast<const f32x4*>(h0 + (size_t)(g * 16 + row) * H_DIM + col0);
      f32x4 v0 = s[0], v1 = s[1];
      u16x8 hv;
      #pragma unroll
      for (int e = 0; e < 4; ++e) { hv[e] = f2bf(v0[e]); hv[4 + e] = f2bf(v1[e]); }
      *reinterpret_cast<u16x8*>(&hb[row * 520 + col0]) = hv;
    }
  }
  __syncthreads();

  const int arow = lane & 15;        // A row (batch) within 16
  const int aoff = (lane >> 4) * 8;  // A k offset
  const int drow = (lane >> 4) * 4;  // D row base
  const int gcol = c * 64 + w * 16 + (lane & 15);
  const u16x8* whv = reinterpret_cast<const u16x8*>(wh);

  for (int t = 0; t < L_DIM; ++t) {
    const size_t obase = ((size_t)t * B_DIM + g * 16) * H_DIM;

    // xp loads early (HBM/L3 latency hides under MFMA loop)
    f32x4 xpv;
    #pragma unroll
    for (int r = 0; r < 4; ++r)
      xpv[r] = out[obase + (size_t)(drow + r) * H_DIM + gcol];

    // ---- z = h . Wh_slice : 32 MFMAs per wave, 4 independent acc chains ----
    f32x4 acc0 = {}, acc1 = {}, acc2 = {}, acc3 = {};
    #pragma unroll
    for (int kt = 0; kt < 16; kt += 2) {
      bf16x8 af0 = __builtin_bit_cast(bf16x8, *reinterpret_cast<const u16x8*>(
          &hb[arow * 520 + kt * 32 + aoff]));
      bf16x8 af1 = __builtin_bit_cast(bf16x8, *reinterpret_cast<const u16x8*>(
          &hb[arow * 520 + (kt + 1) * 32 + aoff]));
      bf16x8 bh0 = __builtin_bit_cast(bf16x8, whv[(size_t)((0 * 4 + w) * 16 + kt) * 64 + lane]);
      bf16x8 bl0 = __builtin_bit_cast(bf16x8, whv[(size_t)((1 * 4 + w) * 16 + kt) * 64 + lane]);
      bf16x8 bh1 = __builtin_bit_cast(bf16x8, whv[(size_t)((0 * 4 + w) * 16 + kt + 1) * 64 + lane]);
      bf16x8 bl1 = __builtin_bit_cast(bf16x8, whv[(size_t)((1 * 4 + w) * 16 + kt + 1) * 64 + lane]);
      acc0 = __builtin_amdgcn_mfma_f32_16x16x32_bf16(af0, bh0, acc0, 0, 0, 0);
      acc1 = __builtin_amdgcn_mfma_f32_16x16x32_bf16(af0, bl0, acc1, 0, 0, 0);
      acc2 = __builtin_amdgcn_mfma_f32_16x16x32_bf16(af1, bh1, acc2, 0, 0, 0);
      acc3 = __builtin_amdgcn_mfma_f32_16x16x32_bf16(af1, bl1, acc3, 0, 0, 0);
    }

    // ---- epilogue: tanh, store out (f32) + own slice (bf16) ----
    const int buf = (t + 1) & 1;
    unsigned short* gs = gbuf + ((size_t)(buf * 8 + g) * 8 + c) * 1024;
    #pragma unroll
    for (int r = 0; r < 4; ++r) {
      float z = acc0[r] + acc1[r] + acc2[r] + acc3[r] + xpv[r];
      float e = __expf(2.0f * z);
      float hv = 1.0f - 2.0f / (e + 1.0f);  // tanh(z)
      out[obase + (size_t)(drow + r) * H_DIM + gcol] = hv;
      gs[(drow + r) * 64 + w * 16 + (lane & 15)] = f2bf(hv);
    }
    if (t == L_DIM - 1) break;

    // ---- cross-WG exchange: arrive, spin, pull all 8 slices -> hb ----
    __syncthreads();  // all waves: slice stores drained (vmcnt0), hb reads done
    if (tid == 0) {
      unsigned int* cp = ctr + (size_t)t * 8 + g;
      __hip_atomic_fetch_add(cp, 1u, __ATOMIC_RELEASE, __HIP_MEMORY_SCOPE_AGENT);
      while (__hip_atomic_load(cp, __ATOMIC_ACQUIRE, __HIP_MEMORY_SCOPE_AGENT) < 8u)
        __builtin_amdgcn_s_sleep(1);
    }
    __syncthreads();
    __threadfence();  // invalidate L1 (and stale L2 lines) before slice reads
    const u16x8* gv = reinterpret_cast<const u16x8*>(gbuf) + (size_t)(buf * 8 + g) * 1024;
    #pragma unroll
    for (int i = 0; i < 4; ++i) {
      int ch = tid + i * 256;               // 1024 chunks of 8 bf16
      int cs = ch >> 7, row = (ch >> 3) & 15, seg = ch & 7;
      u16x8 v = gv[cs * 128 + row * 8 + seg];
      *reinterpret_cast<u16x8*>(&hb[row * 520 + cs * 64 + seg * 8]) = v;
    }
    __syncthreads();  // h_{t+1} in hb before next step's MFMA reads
  }
}

extern "C" void kernel_launch(void* const* d_in, const int* in_sizes, int n_in,
                              void* d_out, int out_size, void* d_ws, size_t ws_size,
                              hipStream_t stream) {
  (void)in_sizes; (void)n_in; (void)out_size; (void)ws_size;
  const float* x  = (const float*)d_in[0];
  const float* h0 = (const float*)d_in[1];
  const float* Wx = (const float*)d_in[2];
  const float* Wh = (const float*)d_in[3];
  const float* bh = (const float*)d_in[4];
  float* out = (float*)d_out;

  unsigned short* WxHi = (unsigned short*)d_ws;       // 131072 u16
  unsigned short* WxLo = WxHi + 131072;               // 131072 u16
  unsigned short* WhHi = WxLo + 131072;               // 262144 u16
  unsigned short* WhLo = WhHi + 262144;               // 262144 u16  (ends at 1572864 B)
  unsigned int*   ctr  = (unsigned int*)((char*)d_ws + 1572864);   // 8192 u32 = 32 KB
  unsigned short* gbuf = (unsigned short*)((char*)d_ws + 1605632); // 131072 u16 = 256 KB

  // per-launch: zero the step counters (deterministic under graph replay)
  hipMemsetAsync(ctr, 0, 32768, stream);

  hipLaunchKernelGGL(pack_weights, dim3(128), dim3(256), 0, stream,
                     Wx, Wh, WxHi, WxLo, WhHi, WhLo);
  hipLaunchKernelGGL(xproj_kernel, dim3(1024, 4), dim3(256), 0, stream,
                     x, WxHi, WxLo, bh, out);

  static bool attr_set = false;
  if (!attr_set) {
    hipFuncSetAttribute(reinterpret_cast<const void*>(rnn_kernel),
                        hipFuncAttributeMaxDynamicSharedMemorySize, 147712);
    attr_set = true;
  }
  hipLaunchKernelGGL(rnn_kernel, dim3(64), dim3(256), 147712, stream,
                     h0, WhHi, WhLo, ctr, gbuf, out);
}

// Round 3
// 3307.986 us; speedup vs baseline: 2.9453x; 2.3851x over previous
//
#include <hip/hip_runtime.h>

#define L_DIM 1024
#define B_DIM 128
#define I_DIM 256
#define H_DIM 512

typedef unsigned short u16x8 __attribute__((ext_vector_type(8)));
typedef __bf16 bf16x8 __attribute__((ext_vector_type(8)));
typedef float f32x4 __attribute__((ext_vector_type(4)));
typedef unsigned long long u64;

static __device__ __forceinline__ unsigned short f2bf(float f) {
  unsigned u = __builtin_bit_cast(unsigned, f);
  u += 0x7FFFu + ((u >> 16) & 1u);
  return (unsigned short)(u >> 16);
}
static __device__ __forceinline__ float bf2f(unsigned short b) {
  return __builtin_bit_cast(float, ((unsigned)b) << 16);
}
static __device__ __forceinline__ bf16x8 ld_frag_g(const unsigned short* p, size_t idx8) {
  return __builtin_bit_cast(bf16x8, reinterpret_cast<const u16x8*>(p)[idx8]);
}

// ---------------------------------------------------------------------------
// Pack Wx and Wh into MFMA B-fragment order, split hi/lo bf16.
// B-frag: lane l holds B[k = kt*32+(l>>4)*8+j][n = nt*16+(l&15)], W stored [n][k].
// Layout: pack[((nt*KT + kt)*64 + lane)*8 + j]
// ---------------------------------------------------------------------------
__global__ void pack_weights(const float* __restrict__ Wx, const float* __restrict__ Wh,
                             unsigned short* __restrict__ WxHi, unsigned short* __restrict__ WxLo,
                             unsigned short* __restrict__ WhHi, unsigned short* __restrict__ WhLo) {
  int tid = blockIdx.x * blockDim.x + threadIdx.x;
  if (tid < 32 * 8 * 64) {  // Wx: 32 ntiles x 8 ktiles (K=256)
    int lane = tid & 63, kt = (tid >> 6) & 7, nt = tid >> 9;
    int n = nt * 16 + (lane & 15), k0 = kt * 32 + (lane >> 4) * 8;
    const float* src = Wx + (size_t)n * I_DIM + k0;
    #pragma unroll
    for (int j = 0; j < 8; ++j) {
      float v = src[j];
      unsigned short hb = f2bf(v);
      WxHi[(size_t)tid * 8 + j] = hb;
      WxLo[(size_t)tid * 8 + j] = f2bf(v - bf2f(hb));
    }
  }
  if (tid < 32 * 16 * 64) {  // Wh: 32 ntiles x 16 ktiles (K=512)
    int lane = tid & 63, kt = (tid >> 6) & 15, nt = tid >> 10;
    int n = nt * 16 + (lane & 15), k0 = kt * 32 + (lane >> 4) * 8;
    const float* src = Wh + (size_t)n * H_DIM + k0;
    #pragma unroll
    for (int j = 0; j < 8; ++j) {
      float v = src[j];
      unsigned short hb = f2bf(v);
      WhHi[(size_t)tid * 8 + j] = hb;
      WhLo[(size_t)tid * 8 + j] = f2bf(v - bf2f(hb));
    }
  }
}

// ---------------------------------------------------------------------------
// xproj: out[m,n] = sum_k x[m,k]*Wx[n,k] + bh[n]  (unchanged)
// ---------------------------------------------------------------------------
__global__ __launch_bounds__(256) void xproj_kernel(const float* __restrict__ x,
    const unsigned short* __restrict__ WxHi, const unsigned short* __restrict__ WxLo,
    const float* __restrict__ bh, float* __restrict__ out) {
  __shared__ unsigned short ahi[128][40];
  __shared__ unsigned short alo[128][40];
  const int tid = threadIdx.x, lane = tid & 63, wid = tid >> 6;
  const int mbase = blockIdx.x * 128, cbase = blockIdx.y * 128;
  const int wrow = (wid >> 1) * 64, wcol = (wid & 1) * 64;
  f32x4 acc[4][4] = {};
  const int srow = tid >> 1, shalf = (tid & 1) * 16;

  for (int kt = 0; kt < 8; ++kt) {
    const f32x4* src = reinterpret_cast<const f32x4*>(
        x + (size_t)(mbase + srow) * I_DIM + kt * 32 + shalf);
    f32x4 v[4];
    v[0] = src[0]; v[1] = src[1]; v[2] = src[2]; v[3] = src[3];
    u16x8 hh[2], ll[2];
    #pragma unroll
    for (int q = 0; q < 2; ++q) {
      #pragma unroll
      for (int e = 0; e < 8; ++e) {
        float f = v[q * 2 + (e >> 2)][e & 3];
        unsigned short hb = f2bf(f);
        hh[q][e] = hb;
        ll[q][e] = f2bf(f - bf2f(hb));
      }
    }
    __syncthreads();
    *reinterpret_cast<u16x8*>(&ahi[srow][shalf]) = hh[0];
    *reinterpret_cast<u16x8*>(&ahi[srow][shalf + 8]) = hh[1];
    *reinterpret_cast<u16x8*>(&alo[srow][shalf]) = ll[0];
    *reinterpret_cast<u16x8*>(&alo[srow][shalf + 8]) = ll[1];
    __syncthreads();

    bf16x8 amh[4], aml[4];
    #pragma unroll
    for (int m = 0; m < 4; ++m) {
      amh[m] = __builtin_bit_cast(bf16x8, *reinterpret_cast<const u16x8*>(
          &ahi[wrow + m * 16 + (lane & 15)][(lane >> 4) * 8]));
      aml[m] = __builtin_bit_cast(bf16x8, *reinterpret_cast<const u16x8*>(
          &alo[wrow + m * 16 + (lane & 15)][(lane >> 4) * 8]));
    }
    bf16x8 bhh[4], bll[4];
    #pragma unroll
    for (int n = 0; n < 4; ++n) {
      int ntg = (cbase + wcol) / 16 + n;
      size_t idx = (size_t)(ntg * 8 + kt) * 64 + lane;
      bhh[n] = ld_frag_g(WxHi, idx);
      bll[n] = ld_frag_g(WxLo, idx);
    }
    #pragma unroll
    for (int m = 0; m < 4; ++m) {
      #pragma unroll
      for (int n = 0; n < 4; ++n) {
        acc[m][n] = __builtin_amdgcn_mfma_f32_16x16x32_bf16(amh[m], bhh[n], acc[m][n], 0, 0, 0);
        acc[m][n] = __builtin_amdgcn_mfma_f32_16x16x32_bf16(aml[m], bhh[n], acc[m][n], 0, 0, 0);
        acc[m][n] = __builtin_amdgcn_mfma_f32_16x16x32_bf16(amh[m], bll[n], acc[m][n], 0, 0, 0);
      }
    }
  }

  #pragma unroll
  for (int n = 0; n < 4; ++n) {
    int col = cbase + wcol + n * 16 + (lane & 15);
    float bv = bh[col];
    #pragma unroll
    for (int m = 0; m < 4; ++m) {
      int rg = mbase + wrow + m * 16 + ((lane >> 4) << 2);
      #pragma unroll
      for (int r = 0; r < 4; ++r)
        out[(size_t)(rg + r) * H_DIM + col] = acc[m][n][r] + bv;
    }
  }
}

// ---------------------------------------------------------------------------
// Recurrence. 64 WGs x 256 thr: g = blk&7 (16 batch rows), c = blk>>3 (64 cols).
// Wave w's Wh fragments (16 cols x 512 k, hi+lo) live in VGPRs (128 VGPRs).
// h_t (16x512 bf16) lives in LDS. Cross-WG h exchange per step via RELAXED
// agent-scope atomics only (no acquire/release fences -> no buffer_wbl2/inv):
//   data u64 stores -> __syncthreads (vmcnt drain) -> tag store;
//   readers spin on tag (relaxed), compiler fence, pull data u64s.
// ---------------------------------------------------------------------------
__global__ __launch_bounds__(256, 1) void rnn_kernel(const float* __restrict__ h0,
    const unsigned short* __restrict__ WhHi, const unsigned short* __restrict__ WhLo,
    unsigned int* __restrict__ tags, u64* __restrict__ gbuf,
    float* __restrict__ out) {
  __shared__ unsigned short hb[16 * 520 + 8];
  const int tid = threadIdx.x, lane = tid & 63, w = tid >> 6;
  const int g = blockIdx.x & 7, c = blockIdx.x >> 3;

  // ---- one-time: Wh fragments -> VGPRs ----
  bf16x8 wfh[16], wfl[16];
  #pragma unroll
  for (int kt = 0; kt < 16; ++kt) {
    size_t idx = (size_t)((c * 4 + w) * 16 + kt) * 64 + lane;
    wfh[kt] = ld_frag_g(WhHi, idx);
    wfl[kt] = ld_frag_g(WhLo, idx);
  }
  // ---- one-time: h0 -> LDS bf16 ----
  for (int i = tid; i < 1024; i += 256) {
    int row = i >> 6, col0 = (i & 63) * 8;
    const f32x4* s = reinterpret_cast<const f32x4*>(h0 + (size_t)(g * 16 + row) * H_DIM + col0);
    f32x4 v0 = s[0], v1 = s[1];
    u16x8 hv;
    #pragma unroll
    for (int e = 0; e < 4; ++e) { hv[e] = f2bf(v0[e]); hv[4 + e] = f2bf(v1[e]); }
    *reinterpret_cast<u16x8*>(&hb[row * 520 + col0]) = hv;
  }
  __syncthreads();

  const int arow = lane & 15;        // A row (batch) within 16; also D col
  const int aoff = (lane >> 4) * 8;  // A k offset
  const int drow = (lane >> 4) * 4;  // D row base
  const int gcol = c * 64 + w * 16 + (lane & 15);
  const int rrow = tid >> 4, rcq = tid & 15;  // readback mapping

  // xp prefetch for t=0
  f32x4 xpv;
  {
    const size_t ob = ((size_t)0 * B_DIM + g * 16) * H_DIM;
    #pragma unroll
    for (int r = 0; r < 4; ++r)
      xpv[r] = out[ob + (size_t)(drow + r) * H_DIM + gcol];
  }

  for (int t = 0; t < L_DIM; ++t) {
    const size_t obase = ((size_t)t * B_DIM + g * 16) * H_DIM;

    // ---- z = h_t . Wh (hi+lo), 32 MFMAs, 4 chains ----
    bf16x8 af[16];
    #pragma unroll
    for (int kt = 0; kt < 16; ++kt)
      af[kt] = __builtin_bit_cast(bf16x8, *reinterpret_cast<const u16x8*>(
          &hb[arow * 520 + kt * 32 + aoff]));
    f32x4 a0 = {}, a1 = {}, a2 = {}, a3 = {};
    #pragma unroll
    for (int kt = 0; kt < 16; kt += 2) {
      a0 = __builtin_amdgcn_mfma_f32_16x16x32_bf16(af[kt], wfh[kt], a0, 0, 0, 0);
      a1 = __builtin_amdgcn_mfma_f32_16x16x32_bf16(af[kt], wfl[kt], a1, 0, 0, 0);
      a2 = __builtin_amdgcn_mfma_f32_16x16x32_bf16(af[kt + 1], wfh[kt + 1], a2, 0, 0, 0);
      a3 = __builtin_amdgcn_mfma_f32_16x16x32_bf16(af[kt + 1], wfl[kt + 1], a3, 0, 0, 0);
    }

    // prefetch xp for t+1 (latency hides under the exchange)
    f32x4 xpn;
    {
      const int tn = (t < L_DIM - 1) ? t + 1 : t;
      const size_t ob = ((size_t)tn * B_DIM + g * 16) * H_DIM;
      #pragma unroll
      for (int r = 0; r < 4; ++r)
        xpn[r] = out[ob + (size_t)(drow + r) * H_DIM + gcol];
    }

    // ---- epilogue: tanh, store out ----
    float hv[4];
    #pragma unroll
    for (int r = 0; r < 4; ++r) {
      float z = a0[r] + a1[r] + a2[r] + a3[r] + xpv[r];
      float e = __expf(2.0f * z);
      hv[r] = 1.0f - 2.0f / (e + 1.0f);  // tanh(z)
      out[obase + (size_t)(drow + r) * H_DIM + gcol] = hv[r];
    }
    xpv = xpn;
    if (t == L_DIM - 1) break;

    const unsigned buf = (t + 1) & 1;

    __syncthreads();  // all waves done reading hb (h_t)
    #pragma unroll
    for (int r = 0; r < 4; ++r)  // own slice into hb (overwrite own cols)
      hb[(drow + r) * 520 + gcol] = f2bf(hv[r]);
    __syncthreads();  // own slice visible WG-wide

    // readback row-major + publish to peers (relaxed agent u64 stores)
    {
      u64 v = *reinterpret_cast<const u64*>(&hb[rrow * 520 + c * 64 + rcq * 4]);
      u64* dst = gbuf + ((size_t)(buf * 8 + g) * 8 + c) * 256 + tid;
      __hip_atomic_store(dst, v, __ATOMIC_RELAXED, __HIP_MEMORY_SCOPE_AGENT);
    }
    __syncthreads();  // drains vmcnt: slice at coherent point
    if (tid == 0)
      __hip_atomic_store(tags + (buf * 8 + g) * 8 + c, (unsigned)(t + 1),
                         __ATOMIC_RELAXED, __HIP_MEMORY_SCOPE_AGENT);

    // poll tags: lane 0/1 of each wave watch sources 2w / 2w+1
    if (lane < 2) {
      unsigned s = 2 * w + lane;
      unsigned int* tp = tags + (buf * 8 + g) * 8 + s;
      while (__hip_atomic_load(tp, __ATOMIC_RELAXED, __HIP_MEMORY_SCOPE_AGENT) < (unsigned)(t + 1))
        __builtin_amdgcn_s_sleep(1);
    }
    asm volatile("" ::: "memory");

    // pull the two sources this wave owns (skip own; already in hb)
    #pragma unroll
    for (int si = 0; si < 2; ++si) {
      int s = 2 * w + si;
      if (s == c) continue;
      const u64* src = gbuf + ((size_t)(buf * 8 + g) * 8 + s) * 256;
      #pragma unroll
      for (int i = 0; i < 4; ++i) {
        int idx = i * 64 + lane;
        u64 v = __hip_atomic_load(src + idx, __ATOMIC_RELAXED, __HIP_MEMORY_SCOPE_AGENT);
        int row = idx >> 4, cq = idx & 15;
        *reinterpret_cast<u64*>(&hb[row * 520 + s * 64 + cq * 4]) = v;
      }
    }
    __syncthreads();  // hb = h_{t+1}
  }
}

extern "C" void kernel_launch(void* const* d_in, const int* in_sizes, int n_in,
                              void* d_out, int out_size, void* d_ws, size_t ws_size,
                              hipStream_t stream) {
  (void)in_sizes; (void)n_in; (void)out_size; (void)ws_size;
  const float* x  = (const float*)d_in[0];
  const float* h0 = (const float*)d_in[1];
  const float* Wx = (const float*)d_in[2];
  const float* Wh = (const float*)d_in[3];
  const float* bh = (const float*)d_in[4];
  float* out = (float*)d_out;

  unsigned short* WxHi = (unsigned short*)d_ws;       // 131072 u16
  unsigned short* WxLo = WxHi + 131072;               // 131072 u16
  unsigned short* WhHi = WxLo + 131072;               // 262144 u16
  unsigned short* WhLo = WhHi + 262144;               // 262144 u16 (ends 1572864 B)
  unsigned int*   tags = (unsigned int*)((char*)d_ws + 1572864);  // 128 u32 (pad to 1KB)
  u64*            gbuf = (u64*)((char*)d_ws + 1573888);           // 32768 u64 = 256 KB

  // per-launch: zero tags (deterministic under graph replay)
  hipMemsetAsync(tags, 0, 1024, stream);

  hipLaunchKernelGGL(pack_weights, dim3(128), dim3(256), 0, stream,
                     Wx, Wh, WxHi, WxLo, WhHi, WhLo);
  hipLaunchKernelGGL(xproj_kernel, dim3(1024, 4), dim3(256), 0, stream,
                     x, WxHi, WxLo, bh, out);
  hipLaunchKernelGGL(rnn_kernel, dim3(64), dim3(256), 0, stream,
                     h0, WhHi, WhLo, tags, gbuf, out);
}

// Round 4
// 3001.631 us; speedup vs baseline: 3.2459x; 1.1021x over previous
//
#include <hip/hip_runtime.h>

#define L_DIM 1024
#define B_DIM 128
#define I_DIM 256
#define H_DIM 512

typedef unsigned short u16x8 __attribute__((ext_vector_type(8)));
typedef __bf16 bf16x8 __attribute__((ext_vector_type(8)));
typedef float f32x4 __attribute__((ext_vector_type(4)));
typedef unsigned long long u64;

static __device__ __forceinline__ unsigned short f2bf(float f) {
  unsigned u = __builtin_bit_cast(unsigned, f);
  u += 0x7FFFu + ((u >> 16) & 1u);
  return (unsigned short)(u >> 16);
}
static __device__ __forceinline__ float bf2f(unsigned short b) {
  return __builtin_bit_cast(float, ((unsigned)b) << 16);
}
static __device__ __forceinline__ bf16x8 ld_frag_g(const unsigned short* p, size_t idx8) {
  return __builtin_bit_cast(bf16x8, reinterpret_cast<const u16x8*>(p)[idx8]);
}

// ---------------------------------------------------------------------------
// Pack Wx and Wh into MFMA B-fragment order, split hi/lo bf16.
// B-frag: lane l holds B[k = kt*32+(l>>4)*8+j][n = nt*16+(l&15)], W stored [n][k].
// Layout: pack[((nt*KT + kt)*64 + lane)*8 + j]
// ---------------------------------------------------------------------------
__global__ void pack_weights(const float* __restrict__ Wx, const float* __restrict__ Wh,
                             unsigned short* __restrict__ WxHi, unsigned short* __restrict__ WxLo,
                             unsigned short* __restrict__ WhHi, unsigned short* __restrict__ WhLo) {
  int tid = blockIdx.x * blockDim.x + threadIdx.x;
  if (tid < 32 * 8 * 64) {  // Wx: 32 ntiles x 8 ktiles (K=256)
    int lane = tid & 63, kt = (tid >> 6) & 7, nt = tid >> 9;
    int n = nt * 16 + (lane & 15), k0 = kt * 32 + (lane >> 4) * 8;
    const float* src = Wx + (size_t)n * I_DIM + k0;
    #pragma unroll
    for (int j = 0; j < 8; ++j) {
      float v = src[j];
      unsigned short hb = f2bf(v);
      WxHi[(size_t)tid * 8 + j] = hb;
      WxLo[(size_t)tid * 8 + j] = f2bf(v - bf2f(hb));
    }
  }
  if (tid < 32 * 16 * 64) {  // Wh: 32 ntiles x 16 ktiles (K=512)
    int lane = tid & 63, kt = (tid >> 6) & 15, nt = tid >> 10;
    int n = nt * 16 + (lane & 15), k0 = kt * 32 + (lane >> 4) * 8;
    const float* src = Wh + (size_t)n * H_DIM + k0;
    #pragma unroll
    for (int j = 0; j < 8; ++j) {
      float v = src[j];
      unsigned short hb = f2bf(v);
      WhHi[(size_t)tid * 8 + j] = hb;
      WhLo[(size_t)tid * 8 + j] = f2bf(v - bf2f(hb));
    }
  }
}

// ---------------------------------------------------------------------------
// xproj: out[m,n] = sum_k x[m,k]*Wx[n,k] + bh[n]  (unchanged)
// ---------------------------------------------------------------------------
__global__ __launch_bounds__(256) void xproj_kernel(const float* __restrict__ x,
    const unsigned short* __restrict__ WxHi, const unsigned short* __restrict__ WxLo,
    const float* __restrict__ bh, float* __restrict__ out) {
  __shared__ unsigned short ahi[128][40];
  __shared__ unsigned short alo[128][40];
  const int tid = threadIdx.x, lane = tid & 63, wid = tid >> 6;
  const int mbase = blockIdx.x * 128, cbase = blockIdx.y * 128;
  const int wrow = (wid >> 1) * 64, wcol = (wid & 1) * 64;
  f32x4 acc[4][4] = {};
  const int srow = tid >> 1, shalf = (tid & 1) * 16;

  for (int kt = 0; kt < 8; ++kt) {
    const f32x4* src = reinterpret_cast<const f32x4*>(
        x + (size_t)(mbase + srow) * I_DIM + kt * 32 + shalf);
    f32x4 v[4];
    v[0] = src[0]; v[1] = src[1]; v[2] = src[2]; v[3] = src[3];
    u16x8 hh[2], ll[2];
    #pragma unroll
    for (int q = 0; q < 2; ++q) {
      #pragma unroll
      for (int e = 0; e < 8; ++e) {
        float f = v[q * 2 + (e >> 2)][e & 3];
        unsigned short hb = f2bf(f);
        hh[q][e] = hb;
        ll[q][e] = f2bf(f - bf2f(hb));
      }
    }
    __syncthreads();
    *reinterpret_cast<u16x8*>(&ahi[srow][shalf]) = hh[0];
    *reinterpret_cast<u16x8*>(&ahi[srow][shalf + 8]) = hh[1];
    *reinterpret_cast<u16x8*>(&alo[srow][shalf]) = ll[0];
    *reinterpret_cast<u16x8*>(&alo[srow][shalf + 8]) = ll[1];
    __syncthreads();

    bf16x8 amh[4], aml[4];
    #pragma unroll
    for (int m = 0; m < 4; ++m) {
      amh[m] = __builtin_bit_cast(bf16x8, *reinterpret_cast<const u16x8*>(
          &ahi[wrow + m * 16 + (lane & 15)][(lane >> 4) * 8]));
      aml[m] = __builtin_bit_cast(bf16x8, *reinterpret_cast<const u16x8*>(
          &alo[wrow + m * 16 + (lane & 15)][(lane >> 4) * 8]));
    }
    bf16x8 bhh[4], bll[4];
    #pragma unroll
    for (int n = 0; n < 4; ++n) {
      int ntg = (cbase + wcol) / 16 + n;
      size_t idx = (size_t)(ntg * 8 + kt) * 64 + lane;
      bhh[n] = ld_frag_g(WxHi, idx);
      bll[n] = ld_frag_g(WxLo, idx);
    }
    #pragma unroll
    for (int m = 0; m < 4; ++m) {
      #pragma unroll
      for (int n = 0; n < 4; ++n) {
        acc[m][n] = __builtin_amdgcn_mfma_f32_16x16x32_bf16(amh[m], bhh[n], acc[m][n], 0, 0, 0);
        acc[m][n] = __builtin_amdgcn_mfma_f32_16x16x32_bf16(aml[m], bhh[n], acc[m][n], 0, 0, 0);
        acc[m][n] = __builtin_amdgcn_mfma_f32_16x16x32_bf16(amh[m], bll[n], acc[m][n], 0, 0, 0);
      }
    }
  }

  #pragma unroll
  for (int n = 0; n < 4; ++n) {
    int col = cbase + wcol + n * 16 + (lane & 15);
    float bv = bh[col];
    #pragma unroll
    for (int m = 0; m < 4; ++m) {
      int rg = mbase + wrow + m * 16 + ((lane >> 4) << 2);
      #pragma unroll
      for (int r = 0; r < 4; ++r)
        out[(size_t)(rg + r) * H_DIM + col] = acc[m][n][r] + bv;
    }
  }
}

// ---------------------------------------------------------------------------
// Recurrence. 64 WGs x 256 thr: g = blk&7 (16 batch rows), c = blk>>3 (64 cols).
// Wh fragments in VGPRs; h_t in LDS (hb). Exchange protocol (relaxed agent
// atomics only, no acquire/release fences):
//   producer: u64 column-fragment store from regs -> wave-local vmcnt(0)
//             -> per-WAVE tag store. No producer-side barrier.
//   consumer: lanes 0..6 spin on the 7 peer tags (own wave index) -> issue
//             7 u64 pulls -> raw s_barrier (hb h_t reads all done) ->
//             ds_write_b16 scatter of pulled + own fragments -> lgkmcnt(0)
//             + raw s_barrier -> next step.
// out[] stores and xp(t+1) loads issue after the tag store (off the
// pre-tag vmcnt drain; they complete during poll/pull).
// ---------------------------------------------------------------------------
__global__ __launch_bounds__(256, 1) void rnn_kernel(const float* __restrict__ h0,
    const unsigned short* __restrict__ WhHi, const unsigned short* __restrict__ WhLo,
    unsigned int* __restrict__ tags, u64* __restrict__ gbuf,
    float* __restrict__ out) {
  __shared__ unsigned short hb[16 * 520];
  const int tid = threadIdx.x, lane = tid & 63, w = tid >> 6;
  const int g = blockIdx.x & 7, c = blockIdx.x >> 3;

  // ---- one-time: Wh fragments -> VGPRs ----
  bf16x8 wfh[16], wfl[16];
  #pragma unroll
  for (int kt = 0; kt < 16; ++kt) {
    size_t idx = (size_t)((c * 4 + w) * 16 + kt) * 64 + lane;
    wfh[kt] = ld_frag_g(WhHi, idx);
    wfl[kt] = ld_frag_g(WhLo, idx);
  }
  // ---- one-time: h0 -> LDS bf16 ----
  for (int i = tid; i < 1024; i += 256) {
    int row = i >> 6, col0 = (i & 63) * 8;
    const f32x4* s = reinterpret_cast<const f32x4*>(h0 + (size_t)(g * 16 + row) * H_DIM + col0);
    f32x4 v0 = s[0], v1 = s[1];
    u16x8 hv;
    #pragma unroll
    for (int e = 0; e < 4; ++e) { hv[e] = f2bf(v0[e]); hv[4 + e] = f2bf(v1[e]); }
    *reinterpret_cast<u16x8*>(&hb[row * 520 + col0]) = hv;
  }
  __syncthreads();

  const int arow = lane & 15;        // A row (batch) within 16; also D col
  const int aoff = (lane >> 4) * 8;  // A k offset
  const int drow = (lane >> 4) * 4;  // D row base
  const int gcol = c * 64 + w * 16 + (lane & 15);
  // producer slot: encodes (col-within-slice)*4 + row-group
  const int pslot = (w * 16 + (lane & 15)) * 4 + (lane >> 4);
  // consumer decode of slot==tid (its producer wave == own w)
  const int ccol = tid >> 2;
  const int crow0 = (tid & 3) * 4;

  // xp prefetch for t=0
  f32x4 xpv;
  #pragma unroll
  for (int r = 0; r < 4; ++r)
    xpv[r] = out[(size_t)(g * 16 + drow + r) * H_DIM + gcol];

  for (int t = 0; t < L_DIM; ++t) {
    const size_t obase = ((size_t)t * B_DIM + g * 16) * H_DIM;

    // ---- z = h_t . Wh (hi+lo), 32 MFMAs, 4 chains ----
    bf16x8 af[16];
    #pragma unroll
    for (int kt = 0; kt < 16; ++kt)
      af[kt] = __builtin_bit_cast(bf16x8, *reinterpret_cast<const u16x8*>(
          &hb[arow * 520 + kt * 32 + aoff]));
    f32x4 a0 = {}, a1 = {}, a2 = {}, a3 = {};
    #pragma unroll
    for (int kt = 0; kt < 16; kt += 2) {
      a0 = __builtin_amdgcn_mfma_f32_16x16x32_bf16(af[kt], wfh[kt], a0, 0, 0, 0);
      a1 = __builtin_amdgcn_mfma_f32_16x16x32_bf16(af[kt], wfl[kt], a1, 0, 0, 0);
      a2 = __builtin_amdgcn_mfma_f32_16x16x32_bf16(af[kt + 1], wfh[kt + 1], a2, 0, 0, 0);
      a3 = __builtin_amdgcn_mfma_f32_16x16x32_bf16(af[kt + 1], wfl[kt + 1], a3, 0, 0, 0);
    }

    float hv[4]; unsigned short hu[4];
    #pragma unroll
    for (int r = 0; r < 4; ++r) {
      float z = a0[r] + a1[r] + a2[r] + a3[r] + xpv[r];
      float e = __expf(2.0f * z);
      hv[r] = 1.0f - 2.0f / (e + 1.0f);  // tanh(z)
      hu[r] = f2bf(hv[r]);
    }

    if (t < L_DIM - 1) {
      const unsigned buf = (t + 1) & 1;
      // ---- publish own column-fragment (1 u64) straight from registers ----
      u64 pv = (u64)hu[0] | ((u64)hu[1] << 16) | ((u64)hu[2] << 32) | ((u64)hu[3] << 48);
      __hip_atomic_store(gbuf + (((size_t)(buf * 8 + g) * 8 + c) * 256 + pslot), pv,
                         __ATOMIC_RELAXED, __HIP_MEMORY_SCOPE_AGENT);
      __builtin_amdgcn_sched_barrier(0);
      asm volatile("s_waitcnt vmcnt(0)" ::: "memory");  // wave-local: pv at coherent point
      __builtin_amdgcn_sched_barrier(0);
      if (lane == 0)
        __hip_atomic_store(tags + ((size_t)((buf * 8 + g) * 8 + c)) * 4 + w,
                           (unsigned)(t + 1), __ATOMIC_RELAXED, __HIP_MEMORY_SCOPE_AGENT);

      // ---- off-critical-path: out stores + xp(t+1) loads (fly during poll) ----
      #pragma unroll
      for (int r = 0; r < 4; ++r)
        out[obase + (size_t)(drow + r) * H_DIM + gcol] = hv[r];
      const size_t obn = ((size_t)(t + 1) * B_DIM + g * 16) * H_DIM;
      #pragma unroll
      for (int r = 0; r < 4; ++r)
        xpv[r] = out[obn + (size_t)(drow + r) * H_DIM + gcol];

      // ---- poll the 7 peer per-wave tags (lanes 0..6) ----
      if (lane < 7) {
        int s = lane + (lane >= c ? 1 : 0);
        const unsigned int* tp = tags + ((size_t)((buf * 8 + g) * 8 + s)) * 4 + w;
        while (__hip_atomic_load(tp, __ATOMIC_RELAXED, __HIP_MEMORY_SCOPE_AGENT)
               < (unsigned)(t + 1)) {}
      }
      __builtin_amdgcn_sched_barrier(0);
      // ---- issue all 7 pulls (slot == tid) ----
      u64 pul[7];
      #pragma unroll
      for (int si = 0; si < 7; ++si) {
        int s = si + (si >= c ? 1 : 0);
        pul[si] = __hip_atomic_load(gbuf + (((size_t)(buf * 8 + g) * 8 + s) * 256 + tid),
                                    __ATOMIC_RELAXED, __HIP_MEMORY_SCOPE_AGENT);
      }
      __builtin_amdgcn_sched_barrier(0);
      __builtin_amdgcn_s_barrier();      // all waves done reading hb (h_t)
      __builtin_amdgcn_sched_barrier(0);
      // own slice from registers
      #pragma unroll
      for (int r = 0; r < 4; ++r)
        hb[(drow + r) * 520 + gcol] = hu[r];
      // peer slices from pulls
      #pragma unroll
      for (int si = 0; si < 7; ++si) {
        int s = si + (si >= c ? 1 : 0);
        #pragma unroll
        for (int dr = 0; dr < 4; ++dr)
          hb[(crow0 + dr) * 520 + s * 64 + ccol] = (unsigned short)(pul[si] >> (16 * dr));
      }
      __builtin_amdgcn_sched_barrier(0);
      asm volatile("s_waitcnt lgkmcnt(0)" ::: "memory");
      __builtin_amdgcn_sched_barrier(0);
      __builtin_amdgcn_s_barrier();      // hb = h_{t+1}
      __builtin_amdgcn_sched_barrier(0);
    } else {
      #pragma unroll
      for (int r = 0; r < 4; ++r)
        out[obase + (size_t)(drow + r) * H_DIM + gcol] = hv[r];
    }
  }
}

extern "C" void kernel_launch(void* const* d_in, const int* in_sizes, int n_in,
                              void* d_out, int out_size, void* d_ws, size_t ws_size,
                              hipStream_t stream) {
  (void)in_sizes; (void)n_in; (void)out_size; (void)ws_size;
  const float* x  = (const float*)d_in[0];
  const float* h0 = (const float*)d_in[1];
  const float* Wx = (const float*)d_in[2];
  const float* Wh = (const float*)d_in[3];
  const float* bh = (const float*)d_in[4];
  float* out = (float*)d_out;

  unsigned short* WxHi = (unsigned short*)d_ws;       // 131072 u16
  unsigned short* WxLo = WxHi + 131072;               // 131072 u16
  unsigned short* WhHi = WxLo + 131072;               // 262144 u16
  unsigned short* WhLo = WhHi + 262144;               // 262144 u16 (ends 1572864 B)
  unsigned int*   tags = (unsigned int*)((char*)d_ws + 1572864);  // 512 u32 = 2KB (pad 1KB->2KB)
  u64*            gbuf = (u64*)((char*)d_ws + 1575936);           // 32768 u64 = 256 KB

  // per-launch: zero tags (deterministic under graph replay)
  hipMemsetAsync(tags, 0, 2048, stream);

  hipLaunchKernelGGL(pack_weights, dim3(128), dim3(256), 0, stream,
                     Wx, Wh, WxHi, WxLo, WhHi, WhLo);
  hipLaunchKernelGGL(xproj_kernel, dim3(1024, 4), dim3(256), 0, stream,
                     x, WxHi, WxLo, bh, out);
  hipLaunchKernelGGL(rnn_kernel, dim3(64), dim3(256), 0, stream,
                     h0, WhHi, WhLo, tags, gbuf, out);
}